// Round 16
// baseline (356.993 us; speedup 1.0000x reference)
//
#include <hip/hip_runtime.h>
#include <hip/hip_bf16.h>

#define TT 512
#define BPB 8                 // batches per block (one wave per layer)
#define NBLK (2048 / BPB)     // 256 blocks = 1 per CU
#define OUTD 64

typedef __attribute__((ext_vector_type(8))) short short8;
typedef __attribute__((ext_vector_type(4))) float f32x4;

__device__ __forceinline__ short f2bf(float x) {  // RNE float->bf16 (staging)
    union { float f; unsigned u; } v; v.f = x;
    unsigned r = (v.u + 0x7FFFu + ((v.u >> 16) & 1u)) >> 16;
    return (short)r;
}
__device__ __forceinline__ unsigned cvtpk2(float lo, float hi) {  // pack 2 bf16
    unsigned r;
    asm("v_cvt_pk_bf16_f32 %0, %1, %2" : "=v"(r) : "v"(lo), "v"(hi));
    return r;
}
__device__ __forceinline__ float sigm(float x) {
    return __builtin_amdgcn_rcpf(1.f + __expf(-x));
}
__device__ __forceinline__ float tanh_fast(float x) {
    return 2.f * sigm(2.f * x) - 1.f;
}

#define ACT_UPDATE(acc, c, hval)                                   \
    {                                                              \
        float gi = sigm((acc)[0]);                                 \
        float gf = sigm((acc)[1]);                                 \
        float gg = tanh_fast((acc)[2]);                            \
        float go = sigm((acc)[3]);                                 \
        (c) = gf * (c) + gi * gg;                                  \
        (hval) = go * tanh_fast((c));                              \
    }

#define MFMA __builtin_amdgcn_mfma_f32_16x16x32_bf16

// REPACK (fixed): lane (col,kg) owns h of units u=4*(4*rhi+i)+kg, b=col&7.
// B-frag slot j needs h[unit kg*8+j][b]:
//   src lane = 16*(j&3) + 8*(kg>>1) + b; src reg = 2*(kg&1) + (j>>2).
// The reg select depends on DEST kg -> must shuffle BOTH candidate regs and
// select at dest (a source-side pre-mux reads the source's kg — R15's bug).
#define REPACK(h0v, h1v, h2v, h3v, frag)                           \
    {                                                              \
        const int base = 8 * (kg >> 1) + b;                        \
        float eA = __shfl((h0v), base);                            \
        float oA = __shfl((h2v), base);                            \
        float eB = __shfl((h0v), base + 16);                       \
        float oB = __shfl((h2v), base + 16);                       \
        float eC = __shfl((h0v), base + 32);                       \
        float oC = __shfl((h2v), base + 32);                       \
        float eD = __shfl((h0v), base + 48);                       \
        float oD = __shfl((h2v), base + 48);                       \
        float eE = __shfl((h1v), base);                            \
        float oE = __shfl((h3v), base);                            \
        float eF = __shfl((h1v), base + 16);                       \
        float oF = __shfl((h3v), base + 16);                       \
        float eG = __shfl((h1v), base + 32);                       \
        float oG = __shfl((h3v), base + 32);                       \
        float eH = __shfl((h1v), base + 48);                       \
        float oH = __shfl((h3v), base + 48);                       \
        const bool ko = (kg & 1) != 0;                             \
        float s0 = ko ? oA : eA;                                   \
        float s1 = ko ? oB : eB;                                   \
        float s2 = ko ? oC : eC;                                   \
        float s3 = ko ? oD : eD;                                   \
        float s4 = ko ? oE : eE;                                   \
        float s5 = ko ? oF : eF;                                   \
        float s6 = ko ? oG : eG;                                   \
        float s7 = ko ? oH : eH;                                   \
        union { unsigned u[4]; short8 s; } hu;                     \
        hu.u[0] = cvtpk2(s0, s1); hu.u[1] = cvtpk2(s2, s3);        \
        hu.u[2] = cvtpk2(s4, s5); hu.u[3] = cvtpk2(s6, s7);        \
        (frag) = hu.s;                                             \
    }

__global__ __launch_bounds__(128, 1) void lstm2_wavelayer_kernel(
    const float* __restrict__ imu,
    const float* __restrict__ w_ih0, const float* __restrict__ w_hh0,
    const float* __restrict__ b_ih0, const float* __restrict__ b_hh0,
    const float* __restrict__ w_ih1, const float* __restrict__ w_hh1,
    const float* __restrict__ b_ih1, const float* __restrict__ b_hh1,
    const float* __restrict__ wf, const float* __restrict__ bf,
    const float* __restrict__ wn, const float* __restrict__ bn,
    float* __restrict__ out)
{
    const int tid = threadIdx.x;
    const int l   = tid & 63;
    const int wv  = tid >> 6;         // 0 = layer-1 wave, 1 = layer-2 wave
    const int col = l & 15;
    const int kg  = l >> 4;
    const int b   = col & 7;          // batch
    const int rhi = col >> 3;         // rep half: owns tiles 4*rhi..4*rhi+3

    __shared__ __align__(16) short xfrag[TT + 2][BPB][8]; // [t][b][k] bf16, k>=6 zero
    __shared__ __align__(16) short h1buf[2][64][8];       // [parity][slot][k] h1 frag
    __shared__ __align__(16) float lasth[BPB][36];

    // ---- stage x
    {
        const int bg0 = blockIdx.x * BPB;
        for (int p = tid; p < BPB * TT; p += 128) {
            const int bb = p >> 9;           // 0..7
            const int t  = p & (TT - 1);
            const float* src = imu + ((size_t)(bg0 + bb) * TT + t) * 6;
            float2 a0 = *(const float2*)(src);
            float2 a1 = *(const float2*)(src + 2);
            float2 a2 = *(const float2*)(src + 4);
            unsigned* dst = (unsigned*)&xfrag[t][bb][0];
            dst[0] = (unsigned short)f2bf(a0.x) | ((unsigned)(unsigned short)f2bf(a0.y) << 16);
            dst[1] = (unsigned short)f2bf(a1.x) | ((unsigned)(unsigned short)f2bf(a1.y) << 16);
            dst[2] = (unsigned short)f2bf(a2.x) | ((unsigned)(unsigned short)f2bf(a2.y) << 16);
            dst[3] = 0u;
        }
        short* px = &xfrag[TT][0][0];
        for (int i = tid; i < 2 * BPB * 8; i += 128) px[i] = 0;
    }

    // ---- A-fragments: wave owns ALL 8 tiles of its layer (proven mapping:
    // row m=col -> gate G=(m&3)*32+4*tau+(m>>2); acc[tp] reg r = gate-type r
    // of unit 4*tp+kg at batch col&7, replicated in col>>3).
    short8 AX[8], AS[8];   // AX: input operand (Wih0-x / Wih1-h1); AS: recurrent
    f32x4 biasv[4];        // bias of the 4 OWNED units (tp = 4*rhi+i)
    #pragma unroll
    for (int tp = 0; tp < 8; ++tp) {
        const int G = (col & 3) * 32 + 4 * tp + (col >> 2);
        if (wv == 0) {
            #pragma unroll
            for (int j = 0; j < 8; ++j) {
                AX[tp][j] = (kg == 0 && j < 6) ? f2bf(w_ih0[G * 6 + j]) : (short)0;
                AS[tp][j] = f2bf(w_hh0[G * 32 + kg * 8 + j]);
            }
        } else {
            #pragma unroll
            for (int j = 0; j < 8; ++j) {
                AX[tp][j] = f2bf(w_ih1[G * 32 + kg * 8 + j]);
                AS[tp][j] = f2bf(w_hh1[G * 32 + kg * 8 + j]);
            }
        }
    }
    #pragma unroll
    for (int i = 0; i < 4; ++i) {
        const int u = 4 * (4 * rhi + i) + kg;
        if (wv == 0) {
            #pragma unroll
            for (int r = 0; r < 4; ++r)
                biasv[i][r] = b_ih0[r * 32 + u] + b_hh0[r * 32 + u];
        } else {
            #pragma unroll
            for (int r = 0; r < 4; ++r)
                biasv[i][r] = b_ih1[r * 32 + u] + b_hh1[r * 32 + u];
        }
    }

    float c0 = 0.f, c1 = 0.f, c2 = 0.f, c3 = 0.f;   // owned cell states
    short8 hfrag = (short8)0;        // wv0: h1 B-frag; wv1: h2 B-frag (in regs)
    short8 xvE = (short8)0, xvO = (short8)0;
    const f32x4 zf = {0.f, 0.f, 0.f, 0.f};

    __syncthreads();

    if (wv == 0) {   // preload x(0)
        short8 t0 = *(const short8*)&xfrag[0][b][0];
        xvE = (kg == 0) ? t0 : (short8)0;
    }

    // ======== PHASE(T): L1 computes h1(T); L2 computes h2(T-1). 1 barrier. ====
#define PHASE(T, RP, WP, XVC, XVL, L2ON)                                        \
    {                                                                           \
        if (wv == 0) {                                                          \
            f32x4 acc[8];                                                       \
            _Pragma("unroll")                                                   \
            for (int tp = 0; tp < 8; ++tp) acc[tp] = MFMA(AX[tp], XVC, zf, 0, 0, 0); \
            _Pragma("unroll")                                                   \
            for (int tp = 0; tp < 8; ++tp) acc[tp] = MFMA(AS[tp], hfrag, acc[tp], 0, 0, 0); \
            float h0, h1v_, h2v_, h3v_;                                         \
            { f32x4 mine = rhi ? acc[4] : acc[0]; mine += biasv[0];             \
              ACT_UPDATE(mine, c0, h0); }                                       \
            { f32x4 mine = rhi ? acc[5] : acc[1]; mine += biasv[1];             \
              ACT_UPDATE(mine, c1, h1v_); }                                     \
            { f32x4 mine = rhi ? acc[6] : acc[2]; mine += biasv[2];             \
              ACT_UPDATE(mine, c2, h2v_); }                                     \
            { f32x4 mine = rhi ? acc[7] : acc[3]; mine += biasv[3];             \
              ACT_UPDATE(mine, c3, h3v_); }                                     \
            REPACK(h0, h1v_, h2v_, h3v_, hfrag);                                \
            if (col < 8)                                                        \
                *(short8*)&h1buf[WP][16 * kg + col][0] = hfrag;                 \
            short8 tnext = *(const short8*)&xfrag[(T) + 1][b][0];               \
            XVL = (kg == 0) ? tnext : (short8)0;                                \
        } else if (L2ON) {                                                      \
            short8 h1v = *(const short8*)&h1buf[RP][16 * kg + b][0];            \
            f32x4 acc[8];                                                       \
            _Pragma("unroll")                                                   \
            for (int tp = 0; tp < 8; ++tp) acc[tp] = MFMA(AS[tp], hfrag, zf, 0, 0, 0); \
            _Pragma("unroll")                                                   \
            for (int tp = 0; tp < 8; ++tp) acc[tp] = MFMA(AX[tp], h1v, acc[tp], 0, 0, 0); \
            float h0, h1v_, h2v_, h3v_;                                         \
            { f32x4 mine = rhi ? acc[4] : acc[0]; mine += biasv[0];             \
              ACT_UPDATE(mine, c0, h0); }                                       \
            { f32x4 mine = rhi ? acc[5] : acc[1]; mine += biasv[1];             \
              ACT_UPDATE(mine, c1, h1v_); }                                     \
            { f32x4 mine = rhi ? acc[6] : acc[2]; mine += biasv[2];             \
              ACT_UPDATE(mine, c2, h2v_); }                                     \
            { f32x4 mine = rhi ? acc[7] : acc[3]; mine += biasv[3];             \
              ACT_UPDATE(mine, c3, h3v_); }                                     \
            REPACK(h0, h1v_, h2v_, h3v_, hfrag);                                \
        }                                                                       \
        __syncthreads();                                                        \
    }

    PHASE(0, 0, 0, xvE, xvO, 0)              // h1(0); L2 idle
    #pragma unroll 1
    for (int t = 1; t < TT - 1; t += 2) {
        PHASE(t,     0, 1, xvO, xvE, 1)      // odd T: WP=1, RP=0
        PHASE(t + 1, 1, 0, xvE, xvO, 1)      // even T: WP=0, RP=1
    }
    PHASE(TT - 1, 0, 1, xvO, xvE, 1)         // T=511 (x prefetch hits pad)

    // ======== epilogue: L2 computes h2(511) from h1buf[1] -> lasth ========
    if (wv == 1) {
        short8 h1v = *(const short8*)&h1buf[1][16 * kg + b][0];  // h1(511)
        f32x4 acc[8];
        #pragma unroll
        for (int tp = 0; tp < 8; ++tp) acc[tp] = MFMA(AS[tp], hfrag, zf, 0, 0, 0);
        #pragma unroll
        for (int tp = 0; tp < 8; ++tp) acc[tp] = MFMA(AX[tp], h1v, acc[tp], 0, 0, 0);
        // ALL lanes own 4 valid (unit,batch) — no col guard (R15 bug #2)
        float h0, h1v_, h2v_, h3v_;
        { f32x4 mine = rhi ? acc[4] : acc[0]; mine += biasv[0];
          ACT_UPDATE(mine, c0, h0); }
        { f32x4 mine = rhi ? acc[5] : acc[1]; mine += biasv[1];
          ACT_UPDATE(mine, c1, h1v_); }
        { f32x4 mine = rhi ? acc[6] : acc[2]; mine += biasv[2];
          ACT_UPDATE(mine, c2, h2v_); }
        { f32x4 mine = rhi ? acc[7] : acc[3]; mine += biasv[3];
          ACT_UPDATE(mine, c3, h3v_); }
        lasth[b][4 * (4 * rhi + 0) + kg] = h0;
        lasth[b][4 * (4 * rhi + 1) + kg] = h1v_;
        lasth[b][4 * (4 * rhi + 2) + kg] = h2v_;
        lasth[b][4 * (4 * rhi + 3) + kg] = h3v_;
    }
    __syncthreads();

    // ======== heads: 4 reps x 128 threads = 8 batches x 64 outputs ========
    #pragma unroll
    for (int rep = 0; rep < 4; ++rep) {
        const int idx = tid + rep * 128;   // 0..511
        const int bb  = idx >> 6;          // 0..7
        const int o   = idx & 63;
        float accF = bf[o], accN = bn[o];
        const float4* wf4 = (const float4*)(wf + o * 32);
        const float4* wn4 = (const float4*)(wn + o * 32);
        const float4* hv4 = (const float4*)&lasth[bb][0];
        #pragma unroll
        for (int k = 0; k < 8; ++k) {
            float4 h4 = hv4[k];
            float4 f4 = wf4[k];
            float4 n4 = wn4[k];
            accF += f4.x * h4.x + f4.y * h4.y + f4.z * h4.z + f4.w * h4.w;
            accN += n4.x * h4.x + n4.y * h4.y + n4.z * h4.z + n4.w * h4.w;
        }
        const size_t bg = (size_t)blockIdx.x * BPB + bb;
        out[bg * OUTD + o] = accF;
        out[(size_t)2048 * OUTD + bg * OUTD + o] = __expf(accN);
    }
}

extern "C" void kernel_launch(void* const* d_in, const int* in_sizes, int n_in,
                              void* d_out, int out_size, void* d_ws, size_t ws_size,
                              hipStream_t stream) {
    const float* imu   = (const float*)d_in[0];
    const float* w_ih0 = (const float*)d_in[1];
    const float* w_hh0 = (const float*)d_in[2];
    const float* b_ih0 = (const float*)d_in[3];
    const float* b_hh0 = (const float*)d_in[4];
    const float* w_ih1 = (const float*)d_in[5];
    const float* w_hh1 = (const float*)d_in[6];
    const float* b_ih1 = (const float*)d_in[7];
    const float* b_hh1 = (const float*)d_in[8];
    const float* wf    = (const float*)d_in[9];
    const float* bf    = (const float*)d_in[10];
    const float* wn    = (const float*)d_in[11];
    const float* bn    = (const float*)d_in[12];
    float* out = (float*)d_out;

    lstm2_wavelayer_kernel<<<dim3(NBLK), dim3(128), 0, stream>>>(
        imu, w_ih0, w_hh0, b_ih0, b_hh0,
        w_ih1, w_hh1, b_ih1, b_hh1,
        wf, bf, wn, bn, out);
}